// Round 1
// baseline (13544.765 us; speedup 1.0000x reference)
//
#include <hip/hip_runtime.h>

#define LEAK 0.2f
#define EPS  1e-5f
#define TS   503
#define SCOPE_AGENT __HIP_MEMORY_SCOPE_AGENT

__device__ __forceinline__ float lrelu(float x){ return x >= 0.f ? x : LEAK * x; }
__device__ __forceinline__ float bflo(unsigned u){ return __uint_as_float(u << 16); }
__device__ __forceinline__ float bfhi(unsigned u){ return __uint_as_float(u & 0xffff0000u); }

// block-wide reduce (sum or max), works for blockDim 64..1024 (multiple of 64)
template<bool MAXOP>
__device__ __forceinline__ float bred(float v, float* red){
  #pragma unroll
  for (int off = 32; off; off >>= 1){
    float o = __shfl_xor(v, off);
    v = MAXOP ? fmaxf(v, o) : (v + o);
  }
  int nw = blockDim.x >> 6;
  int wv = threadIdx.x >> 6, ln = threadIdx.x & 63;
  __syncthreads();
  if (ln == 0) red[wv] = v;
  __syncthreads();
  if (wv == 0){
    float x = (ln < nw) ? red[ln] : (MAXOP ? -3.402823466e38f : 0.f);
    #pragma unroll
    for (int off = 8; off; off >>= 1){
      float o = __shfl_xor(x, off);
      x = MAXOP ? fmaxf(x, o) : (x + o);
    }
    if (ln == 0) red[0] = x;
  }
  __syncthreads();
  return red[0];
}

// ---- attention ----
// w2[row] = leaky(W2w[row,:]·hidden + W2b[row]); one wave per row
__global__ void k_w2(const float* __restrict__ W2w, const float* __restrict__ W2b,
                     const float* __restrict__ hidden, float* __restrict__ w2v){
  int wave = threadIdx.x >> 6, lane = threadIdx.x & 63;
  int row = blockIdx.x*4 + wave;
  const float* wr = W2w + (size_t)row*2048;
  float acc = 0.f;
  #pragma unroll
  for (int k = 0; k < 8; ++k){
    int base = 4*lane + 256*k;
    float4 w = *(const float4*)(wr + base);
    float4 h = *(const float4*)(hidden + base);
    acc = fmaf(w.x,h.x, fmaf(w.y,h.y, fmaf(w.z,h.z, fmaf(w.w,h.w, acc))));
  }
  #pragma unroll
  for (int off = 32; off; off >>= 1) acc += __shfl_xor(acc, off);
  if (lane == 0) w2v[row] = lrelu(acc + W2b[row]);
}

// score[i] = sum_j leaky(enc[i,:]·W1[j,:] + W1b[j]) * Vw[j] + w2[i]*Vw[2048] + Vb
__global__ void k_score(const float* __restrict__ enc, const float* __restrict__ W1w,
                        const float* __restrict__ W1b, const float* __restrict__ Vw,
                        const float* __restrict__ Vb, const float* __restrict__ w2v,
                        float* __restrict__ score){
  __shared__ float sW1[2048*6];
  int tid = threadIdx.x;
  for (int idx = tid; idx < 2048*6; idx += 256) sW1[idx] = W1w[idx];
  __syncthreads();
  int wave = tid >> 6, lane = tid & 63;
  int i = blockIdx.x*4 + wave;
  float e0 = enc[(size_t)i*6+0], e1 = enc[(size_t)i*6+1], e2 = enc[(size_t)i*6+2];
  float e3 = enc[(size_t)i*6+3], e4 = enc[(size_t)i*6+4], e5 = enc[(size_t)i*6+5];
  float acc = 0.f;
  for (int jj = 0; jj < 32; ++jj){
    int j = lane + 64*jj;
    const float* wr = sW1 + j*6;
    float a = fmaf(e0,wr[0], fmaf(e1,wr[1], fmaf(e2,wr[2],
              fmaf(e3,wr[3], fmaf(e4,wr[4], fmaf(e5,wr[5], W1b[j]))))));
    acc = fmaf(lrelu(a), Vw[j], acc);
  }
  #pragma unroll
  for (int off = 32; off; off >>= 1) acc += __shfl_xor(acc, off);
  if (lane == 0) score[i] = acc + w2v[i]*Vw[2048] + Vb[0];
}

// bn1 + leaky + softmax + context; single block, 1024 threads (2 elems/thread)
__global__ void k_softctx(const float* __restrict__ enc, const float* __restrict__ score,
                          const float* g1, const float* b1, float* __restrict__ ctx){
  __shared__ float red[16];
  int tid = threadIdx.x;
  float s0 = score[tid], s1 = score[tid + 1024];
  float mean = bred<false>(s0 + s1, red) * (1.f/2048.f);
  float d0 = s0 - mean, d1 = s1 - mean;
  float var = bred<false>(d0*d0 + d1*d1, red) * (1.f/2048.f);
  float iv = rsqrtf(var + EPS);
  float g = g1[0], b = b1[0];
  float v0 = lrelu(d0*iv*g + b), v1 = lrelu(d1*iv*g + b);
  float mx = bred<true>(fmaxf(v0, v1), red);
  float e0 = expf(v0 - mx), e1 = expf(v1 - mx);
  float se = bred<false>(e0 + e1, red);
  float w0 = e0/se, w1 = e1/se;
  #pragma unroll
  for (int c = 0; c < 6; ++c){
    ctx[c*2048 + tid]        = enc[(size_t)tid*6 + c] * w0;
    ctx[c*2048 + tid + 1024] = enc[(size_t)(tid+1024)*6 + c] * w1;
  }
}

// ---- CNN ----
__global__ void k_conv(const float* __restrict__ in, int Lin,
                       float* __restrict__ out, int Lout,
                       const float* __restrict__ w, const float* __restrict__ b, int K){
  int idx = blockIdx.x*256 + threadIdx.x;
  if (idx >= 6*Lout) return;
  int o = idx / Lout, x = idx - o*Lout;
  float acc = b[o];
  for (int i = 0; i < 6; ++i){
    const float* ir = in + i*Lin + x;
    const float* wr = w + (o*6 + i)*K;
    for (int k = 0; k < K; ++k) acc = fmaf(ir[k], wr[k], acc);
  }
  out[o*Lout + x] = lrelu(acc);
}

__global__ void k_pool(const float* __restrict__ in, int Lin, float* __restrict__ out, int Lout){
  int idx = blockIdx.x*256 + threadIdx.x;
  if (idx >= 6*Lout) return;
  int o = idx / Lout, x = idx - o*Lout;
  out[idx] = fmaxf(in[o*Lin + 2*x], in[o*Lin + 2*x + 1]);
}

__global__ void k_bn2stats(const float* __restrict__ in, float* m6, float* i6){
  __shared__ float red[16];
  for (int c = 0; c < 6; ++c){
    float s = 0.f, s2 = 0.f;
    for (int i = threadIdx.x; i < 1006; i += 256){
      float v = in[c*1006 + i]; s += v; s2 += v*v;
    }
    s  = bred<false>(s, red);
    s2 = bred<false>(s2, red);
    if (threadIdx.x == 0){
      float m = s / 1006.f;
      float var = s2 / 1006.f - m*m;
      m6[c] = m; i6[c] = rsqrtf(var + EPS);
    }
  }
}

// bn2 + maxpool2 + transpose -> seq[t*6+c]
__global__ void k_seq(const float* __restrict__ cb4, const float* m6, const float* i6,
                      const float* g2, const float* b2, float* __restrict__ seq){
  int idx = blockIdx.x*256 + threadIdx.x;
  if (idx >= TS*6) return;
  int c = idx % 6, t = idx / 6;
  float m = m6[c], iv = i6[c], g = g2[c], b = b2[c];
  float v0 = (cb4[c*1006 + 2*t]     - m)*iv*g + b;
  float v1 = (cb4[c*1006 + 2*t + 1] - m)*iv*g + b;
  seq[idx] = fmaxf(v0, v1);
}

// gihat[t,row] = seq[t,:]·Wi[row,:] + bi[row]   (bh added in GRU combine)
__global__ void k_gihat(const float* __restrict__ seq, const float* __restrict__ Wi,
                        const float* __restrict__ bi, float* __restrict__ gihat){
  int row = blockIdx.x*256 + threadIdx.x;   // < 6144
  int t = blockIdx.y;
  const float* s = seq + t*6;
  const float* w = Wi + (size_t)row*6;
  float v = fmaf(s[0],w[0], fmaf(s[1],w[1], fmaf(s[2],w[2],
            fmaf(s[3],w[3], fmaf(s[4],w[4], fmaf(s[5],w[5], bi[row]))))));
  gihat[(size_t)t*6144 + row] = v;
}

// ---- GRU: 256 co-resident WGs, LDS-resident bf16 Wh, flag-based step sync ----
#define GRU_SMEM (24*2048*2 + 2048*4 + 24*4 + 8*4)

__global__ void __launch_bounds__(256, 1)
k_gru(const float* __restrict__ Wh, const float* __restrict__ bh,
      const float* __restrict__ hidden, const float* __restrict__ gihat,
      float* hbuf, int* flags, float* __restrict__ xs, float* __restrict__ dout){
  extern __shared__ char smem[];
  ushort* Wl      = (ushort*)smem;                        // [24][2048] bf16
  float*  h_lds   = (float*)(smem + 24*2048*2);           // [2048]
  float*  gh_lds  = (float*)(smem + 24*2048*2 + 2048*4);  // [24]
  float*  hnew_lds = gh_lds + 24;                         // [8]
  const int tid = threadIdx.x, wg = blockIdx.x;
  const int lane = tid & 63, wave = tid >> 6;
  const int hbase = wg << 3;   // 8 h-indices per WG

  // stage & convert weights: local rows 0..7 = r, 8..15 = z, 16..23 = n
  for (int idx = tid; idx < 24*2048; idx += 256){
    int lr = idx >> 11, col = idx & 2047;
    int grow = (lr < 8) ? (hbase + lr)
             : (lr < 16) ? (2048 + hbase + lr - 8)
                         : (4096 + hbase + lr - 16);
    unsigned u = __float_as_uint(Wh[(size_t)grow*2048 + col]);
    Wl[idx] = (ushort)((u + 0x7fffu + ((u >> 16) & 1u)) >> 16);   // RNE to bf16
  }
  float bhr = 0.f, bhz = 0.f, bhn = 0.f;
  if (tid < 8){
    bhr = bh[hbase + tid];
    bhz = bh[2048 + hbase + tid];
    bhn = bh[4096 + hbase + tid];
  }
  __syncthreads();

  for (int t = 0; t < TS; ++t){
    // prefetch per-step gate biases (independent of h -> overlaps with spin)
    float gr = 0.f, gz = 0.f, gn = 0.f;
    if (tid < 8){
      const float* gp = gihat + (size_t)t*6144 + hbase + tid;
      gr = gp[0]; gz = gp[2048]; gn = gp[4096];
    }
    if (t == 0){
      for (int i = tid; i < 2048; i += 256) h_lds[i] = hidden[i];
    } else {
      while (__hip_atomic_load(flags + tid, __ATOMIC_ACQUIRE, SCOPE_AGENT) < t)
        __builtin_amdgcn_s_sleep(1);
      __syncthreads();
      const float* hb = hbuf + ((t - 1) & 1)*2048;
      for (int i = tid; i < 2048; i += 256)
        h_lds[i] = __hip_atomic_load(hb + i, __ATOMIC_RELAXED, SCOPE_AGENT);
    }
    __syncthreads();

    // per-lane h fragment (same layout for every row)
    float hreg[32];
    #pragma unroll
    for (int k = 0; k < 4; ++k){
      const float* hp = h_lds + 8*lane + 512*k;
      float4 a = *(const float4*)hp;
      float4 b = *(const float4*)(hp + 4);
      hreg[8*k+0]=a.x; hreg[8*k+1]=a.y; hreg[8*k+2]=a.z; hreg[8*k+3]=a.w;
      hreg[8*k+4]=b.x; hreg[8*k+5]=b.y; hreg[8*k+6]=b.z; hreg[8*k+7]=b.w;
    }
    // 24 dot products: wave w owns rows 6w..6w+5
    #pragma unroll
    for (int rr = 0; rr < 6; ++rr){
      int lr = wave*6 + rr;
      const ushort* wrow = Wl + lr*2048 + 8*lane;
      float acc = 0.f;
      #pragma unroll
      for (int k = 0; k < 4; ++k){
        uint4 wv = *(const uint4*)(wrow + (k << 9));
        acc = fmaf(bflo(wv.x), hreg[8*k+0], acc);
        acc = fmaf(bfhi(wv.x), hreg[8*k+1], acc);
        acc = fmaf(bflo(wv.y), hreg[8*k+2], acc);
        acc = fmaf(bfhi(wv.y), hreg[8*k+3], acc);
        acc = fmaf(bflo(wv.z), hreg[8*k+4], acc);
        acc = fmaf(bfhi(wv.z), hreg[8*k+5], acc);
        acc = fmaf(bflo(wv.w), hreg[8*k+6], acc);
        acc = fmaf(bfhi(wv.w), hreg[8*k+7], acc);
      }
      #pragma unroll
      for (int off = 32; off; off >>= 1) acc += __shfl_xor(acc, off);
      if (lane == 0) gh_lds[lr] = acc;
    }
    __syncthreads();
    // gate combine on 8 threads
    if (tid < 8){
      float r  = 1.f/(1.f + expf(-(gr + bhr + gh_lds[tid])));
      float z  = 1.f/(1.f + expf(-(gz + bhz + gh_lds[8 + tid])));
      float ng = tanhf(gn + r*(gh_lds[16 + tid] + bhn));
      float hold = h_lds[hbase + tid];
      float hnew = (1.f - z)*ng + z*hold;
      xs[(size_t)t*2048 + hbase + tid] = hnew;
      if (t == TS - 1) dout[4 + hbase + tid] = hnew;
      hnew_lds[tid] = hnew;
    }
    __syncthreads();
    // publish slice + flag (release orders the h stores before the flag)
    if (tid == 0){
      float* hb = hbuf + (t & 1)*2048 + hbase;
      #pragma unroll
      for (int j = 0; j < 8; ++j)
        __hip_atomic_store(hb + j, hnew_lds[j], __ATOMIC_RELAXED, SCOPE_AGENT);
      __hip_atomic_store(flags + wg, t + 1, __ATOMIC_RELEASE, SCOPE_AGENT);
    }
  }
}

// ---- head ----
// y1[t,j] = sum_k leaky(xs[t,k]) * l1w[j,k] + l1b[j]; 32x32 tiles, 2x2/thread
__global__ void k_lin1(const float* __restrict__ xs, const float* __restrict__ W,
                       const float* __restrict__ B, float* __restrict__ y1){
  __shared__ float xT[32][36];
  __shared__ float wT[32][36];
  int tid = threadIdx.x;
  int m0 = blockIdx.y*32, n0 = blockIdx.x*32;
  int lm = tid >> 3, lk = (tid & 7)*4;
  int tx = tid & 15, ty = tid >> 4;
  float acc00=0.f, acc01=0.f, acc10=0.f, acc11=0.f;
  for (int k0 = 0; k0 < 2048; k0 += 32){
    float4 xv = make_float4(0.f,0.f,0.f,0.f);
    int tt = m0 + lm;
    if (tt < TS) xv = *(const float4*)(xs + (size_t)tt*2048 + k0 + lk);
    xT[lk+0][lm] = lrelu(xv.x); xT[lk+1][lm] = lrelu(xv.y);
    xT[lk+2][lm] = lrelu(xv.z); xT[lk+3][lm] = lrelu(xv.w);
    float4 wv = make_float4(0.f,0.f,0.f,0.f);
    int jj = n0 + lm;
    if (jj < 400) wv = *(const float4*)(W + (size_t)jj*2048 + k0 + lk);
    wT[lk+0][lm] = wv.x; wT[lk+1][lm] = wv.y; wT[lk+2][lm] = wv.z; wT[lk+3][lm] = wv.w;
    __syncthreads();
    #pragma unroll
    for (int k = 0; k < 32; ++k){
      float2 a = *(const float2*)&xT[k][2*ty];
      float2 b = *(const float2*)&wT[k][2*tx];
      acc00 = fmaf(a.x, b.x, acc00); acc01 = fmaf(a.x, b.y, acc01);
      acc10 = fmaf(a.y, b.x, acc10); acc11 = fmaf(a.y, b.y, acc11);
    }
    __syncthreads();
  }
  int t0 = m0 + 2*ty, j0 = n0 + 2*tx;
  if (t0 < TS){
    if (j0 < 400)   y1[t0*400 + j0]   = acc00 + B[j0];
    if (j0+1 < 400) y1[t0*400 + j0+1] = acc01 + B[j0+1];
  }
  if (t0+1 < TS){
    if (j0 < 400)   y1[(t0+1)*400 + j0]   = acc10 + B[j0];
    if (j0+1 < 400) y1[(t0+1)*400 + j0+1] = acc11 + B[j0+1];
  }
}

__global__ void k_bn3p(const float* __restrict__ y1, float* __restrict__ part){
  __shared__ float red[16];
  float s = 0.f, s2 = 0.f;
  for (int idx = blockIdx.x*256 + threadIdx.x; idx < TS*400; idx += 64*256){
    float v = y1[idx]; s += v; s2 += v*v;
  }
  s  = bred<false>(s, red);
  s2 = bred<false>(s2, red);
  if (threadIdx.x == 0){ part[blockIdx.x] = s; part[64 + blockIdx.x] = s2; }
}

__global__ void k_bn3f(const float* __restrict__ part, float* __restrict__ stats){
  int ln = threadIdx.x;
  float s = part[ln], s2 = part[64 + ln];
  #pragma unroll
  for (int off = 32; off; off >>= 1){ s += __shfl_xor(s, off); s2 += __shfl_xor(s2, off); }
  if (ln == 0){
    float m = s / (float)(TS*400);
    float var = s2 / (float)(TS*400) - m*m;
    stats[0] = m; stats[1] = rsqrtf(var + EPS);
  }
}

__global__ void k_x2(const float* __restrict__ y1, const float* __restrict__ stats,
                     const float* g3, const float* b3, const float* __restrict__ l2w,
                     const float* l2b, float* __restrict__ x2){
  int t = blockIdx.x, ln = threadIdx.x;
  float m = stats[0], iv = stats[1], g = g3[0], b = b3[0];
  float acc = 0.f;
  for (int j = ln; j < 400; j += 64)
    acc = fmaf(lrelu((y1[t*400 + j] - m)*iv*g + b), l2w[j], acc);
  #pragma unroll
  for (int off = 32; off; off >>= 1) acc += __shfl_xor(acc, off);
  if (ln == 0) x2[t] = lrelu(acc + l2b[0]);
}

__global__ void k_head(const float* __restrict__ x2, const float* __restrict__ last,
                       const float* __restrict__ l3w, const float* __restrict__ l3b,
                       const float* __restrict__ l4w, const float* __restrict__ l4b,
                       float* __restrict__ out){
  __shared__ float o1[50];
  int tid = threadIdx.x;
  if (tid < 50){
    float acc = l3b[tid];
    const float* wr = l3w + tid*507;
    for (int i = 0; i < TS; ++i) acc = fmaf(x2[i], wr[i], acc);
    for (int i = 0; i < 4; ++i)  acc = fmaf(last[i], wr[TS + i], acc);
    o1[tid] = lrelu(acc);
  }
  __syncthreads();
  if (tid < 4){
    float acc = l4b[tid];
    const float* wr = l4w + tid*50;
    for (int k = 0; k < 50; ++k) acc = fmaf(o1[k], wr[k], acc);
    out[tid] = acc;
  }
}

// ---- workspace layout (bytes) ----
#define OFF_FLAGS   0u
#define OFF_BN2M    1024u
#define OFF_BN2I    1056u
#define OFF_BN3P    2048u
#define OFF_BN3S    2560u
#define OFF_W2      4096u
#define OFF_SCORE   12288u
#define OFF_X2      20480u
#define OFF_CTX     24576u
#define OFF_CB1     73728u
#define OFF_CB2     122880u
#define OFF_CP1     172032u
#define OFF_CB3     196608u
#define OFF_CB4     221184u
#define OFF_SEQ     245760u
#define OFF_HBUF    258048u
#define OFF_GIHAT   274432u
#define OFF_XS      12636160u
#define OFF_Y1      16756736u

extern "C" void kernel_launch(void* const* d_in, const int* in_sizes, int n_in,
                              void* d_out, int out_size, void* d_ws, size_t ws_size,
                              hipStream_t stream){
  const float* last   = (const float*)d_in[0];
  const float* hidden = (const float*)d_in[1];
  const float* enc    = (const float*)d_in[2];
  const float* W1w = (const float*)d_in[3];
  const float* W1b = (const float*)d_in[4];
  const float* W2w = (const float*)d_in[5];
  const float* W2b = (const float*)d_in[6];
  const float* Vw  = (const float*)d_in[7];
  const float* Vb  = (const float*)d_in[8];
  const float* g1  = (const float*)d_in[9];
  const float* b1  = (const float*)d_in[10];
  const float* c1w = (const float*)d_in[11]; const float* c1b = (const float*)d_in[12];
  const float* c2w = (const float*)d_in[13]; const float* c2b = (const float*)d_in[14];
  const float* c3w = (const float*)d_in[15]; const float* c3b = (const float*)d_in[16];
  const float* c4w = (const float*)d_in[17]; const float* c4b = (const float*)d_in[18];
  const float* g2  = (const float*)d_in[19]; const float* b2  = (const float*)d_in[20];
  const float* Wi  = (const float*)d_in[21]; const float* Wh  = (const float*)d_in[22];
  const float* bi  = (const float*)d_in[23]; const float* bhp = (const float*)d_in[24];
  const float* l1w = (const float*)d_in[25]; const float* l1b = (const float*)d_in[26];
  const float* g3  = (const float*)d_in[27]; const float* b3  = (const float*)d_in[28];
  const float* l2w = (const float*)d_in[29]; const float* l2b = (const float*)d_in[30];
  const float* l3w = (const float*)d_in[31]; const float* l3b = (const float*)d_in[32];
  const float* l4w = (const float*)d_in[33]; const float* l4b = (const float*)d_in[34];
  float* out = (float*)d_out;
  char* ws = (char*)d_ws;

  int*   flags = (int*)(ws + OFF_FLAGS);
  float* bn2m  = (float*)(ws + OFF_BN2M);
  float* bn2i  = (float*)(ws + OFF_BN2I);
  float* bn3p  = (float*)(ws + OFF_BN3P);
  float* bn3s  = (float*)(ws + OFF_BN3S);
  float* w2v   = (float*)(ws + OFF_W2);
  float* score = (float*)(ws + OFF_SCORE);
  float* x2    = (float*)(ws + OFF_X2);
  float* ctx   = (float*)(ws + OFF_CTX);
  float* cb1   = (float*)(ws + OFF_CB1);
  float* cb2   = (float*)(ws + OFF_CB2);
  float* cp1   = (float*)(ws + OFF_CP1);
  float* cb3   = (float*)(ws + OFF_CB3);
  float* cb4   = (float*)(ws + OFF_CB4);
  float* seq   = (float*)(ws + OFF_SEQ);
  float* hbuf  = (float*)(ws + OFF_HBUF);
  float* gihat = (float*)(ws + OFF_GIHAT);
  float* xs    = (float*)(ws + OFF_XS);
  float* y1    = (float*)(ws + OFF_Y1);

  hipMemsetAsync(flags, 0, 1024, stream);

  k_w2<<<512, 256, 0, stream>>>(W2w, W2b, hidden, w2v);
  k_score<<<512, 256, 0, stream>>>(enc, W1w, W1b, Vw, Vb, w2v, score);
  k_softctx<<<1, 1024, 0, stream>>>(enc, score, g1, b1, ctx);

  k_conv<<<(6*2038 + 255)/256, 256, 0, stream>>>(ctx, 2048, cb1, 2038, c1w, c1b, 11);
  k_conv<<<(6*2028 + 255)/256, 256, 0, stream>>>(cb1, 2038, cb2, 2028, c2w, c2b, 11);
  k_pool<<<(6*1014 + 255)/256, 256, 0, stream>>>(cb2, 2028, cp1, 1014);
  k_conv<<<(6*1010 + 255)/256, 256, 0, stream>>>(cp1, 1014, cb3, 1010, c3w, c3b, 5);
  k_conv<<<(6*1006 + 255)/256, 256, 0, stream>>>(cb3, 1010, cb4, 1006, c4w, c4b, 5);
  k_bn2stats<<<1, 256, 0, stream>>>(cb4, bn2m, bn2i);
  k_seq<<<12, 256, 0, stream>>>(cb4, bn2m, bn2i, g2, b2, seq);
  k_gihat<<<dim3(24, TS), 256, 0, stream>>>(seq, Wi, bi, gihat);

  hipFuncSetAttribute((const void*)k_gru, hipFuncAttributeMaxDynamicSharedMemorySize,
                      (int)GRU_SMEM);
  void* kargs[8] = {(void*)&Wh, (void*)&bhp, (void*)&hidden, (void*)&gihat,
                    (void*)&hbuf, (void*)&flags, (void*)&xs, (void*)&out};
  hipLaunchCooperativeKernel((const void*)k_gru, dim3(256), dim3(256), kargs,
                             (unsigned)GRU_SMEM, stream);

  k_lin1<<<dim3(13, 16), 256, 0, stream>>>(xs, l1w, l1b, y1);
  k_bn3p<<<64, 256, 0, stream>>>(y1, bn3p);
  k_bn3f<<<1, 64, 0, stream>>>(bn3p, bn3s);
  k_x2<<<TS, 64, 0, stream>>>(y1, bn3s, g3, b3, l2w, l2b, x2);
  k_head<<<1, 64, 0, stream>>>(x2, last, l3w, l3b, l4w, l4b, out);
}

// Round 2
// 3269.439 us; speedup vs baseline: 4.1428x; 4.1428x over previous
//
#include <hip/hip_runtime.h>

#define LEAK 0.2f
#define EPS  1e-5f
#define TS   503
#define SCOPE_AGENT __HIP_MEMORY_SCOPE_AGENT
typedef unsigned long long ull;

__device__ __forceinline__ float lrelu(float x){ return x >= 0.f ? x : LEAK * x; }
__device__ __forceinline__ float bflo(unsigned u){ return __uint_as_float(u << 16); }
__device__ __forceinline__ float bfhi(unsigned u){ return __uint_as_float(u & 0xffff0000u); }

// block-wide reduce (sum or max), works for blockDim 64..1024 (multiple of 64)
template<bool MAXOP>
__device__ __forceinline__ float bred(float v, float* red){
  #pragma unroll
  for (int off = 32; off; off >>= 1){
    float o = __shfl_xor(v, off);
    v = MAXOP ? fmaxf(v, o) : (v + o);
  }
  int nw = blockDim.x >> 6;
  int wv = threadIdx.x >> 6, ln = threadIdx.x & 63;
  __syncthreads();
  if (ln == 0) red[wv] = v;
  __syncthreads();
  if (wv == 0){
    float x = (ln < nw) ? red[ln] : (MAXOP ? -3.402823466e38f : 0.f);
    #pragma unroll
    for (int off = 8; off; off >>= 1){
      float o = __shfl_xor(x, off);
      x = MAXOP ? fmaxf(x, o) : (x + o);
    }
    if (ln == 0) red[0] = x;
  }
  __syncthreads();
  return red[0];
}

// ---- attention ----
__global__ void k_w2(const float* __restrict__ W2w, const float* __restrict__ W2b,
                     const float* __restrict__ hidden, float* __restrict__ w2v){
  int wave = threadIdx.x >> 6, lane = threadIdx.x & 63;
  int row = blockIdx.x*4 + wave;
  const float* wr = W2w + (size_t)row*2048;
  float acc = 0.f;
  #pragma unroll
  for (int k = 0; k < 8; ++k){
    int base = 4*lane + 256*k;
    float4 w = *(const float4*)(wr + base);
    float4 h = *(const float4*)(hidden + base);
    acc = fmaf(w.x,h.x, fmaf(w.y,h.y, fmaf(w.z,h.z, fmaf(w.w,h.w, acc))));
  }
  #pragma unroll
  for (int off = 32; off; off >>= 1) acc += __shfl_xor(acc, off);
  if (lane == 0) w2v[row] = lrelu(acc + W2b[row]);
}

__global__ void k_score(const float* __restrict__ enc, const float* __restrict__ W1w,
                        const float* __restrict__ W1b, const float* __restrict__ Vw,
                        const float* __restrict__ Vb, const float* __restrict__ w2v,
                        float* __restrict__ score){
  __shared__ float sW1[2048*6];
  int tid = threadIdx.x;
  for (int idx = tid; idx < 2048*6; idx += 256) sW1[idx] = W1w[idx];
  __syncthreads();
  int wave = tid >> 6, lane = tid & 63;
  int i = blockIdx.x*4 + wave;
  float e0 = enc[(size_t)i*6+0], e1 = enc[(size_t)i*6+1], e2 = enc[(size_t)i*6+2];
  float e3 = enc[(size_t)i*6+3], e4 = enc[(size_t)i*6+4], e5 = enc[(size_t)i*6+5];
  float acc = 0.f;
  for (int jj = 0; jj < 32; ++jj){
    int j = lane + 64*jj;
    const float* wr = sW1 + j*6;
    float a = fmaf(e0,wr[0], fmaf(e1,wr[1], fmaf(e2,wr[2],
              fmaf(e3,wr[3], fmaf(e4,wr[4], fmaf(e5,wr[5], W1b[j]))))));
    acc = fmaf(lrelu(a), Vw[j], acc);
  }
  #pragma unroll
  for (int off = 32; off; off >>= 1) acc += __shfl_xor(acc, off);
  if (lane == 0) score[i] = acc + w2v[i]*Vw[2048] + Vb[0];
}

__global__ void k_softctx(const float* __restrict__ enc, const float* __restrict__ score,
                          const float* g1, const float* b1, float* __restrict__ ctx){
  __shared__ float red[16];
  int tid = threadIdx.x;
  float s0 = score[tid], s1 = score[tid + 1024];
  float mean = bred<false>(s0 + s1, red) * (1.f/2048.f);
  float d0 = s0 - mean, d1 = s1 - mean;
  float var = bred<false>(d0*d0 + d1*d1, red) * (1.f/2048.f);
  float iv = rsqrtf(var + EPS);
  float g = g1[0], b = b1[0];
  float v0 = lrelu(d0*iv*g + b), v1 = lrelu(d1*iv*g + b);
  float mx = bred<true>(fmaxf(v0, v1), red);
  float e0 = expf(v0 - mx), e1 = expf(v1 - mx);
  float se = bred<false>(e0 + e1, red);
  float w0 = e0/se, w1 = e1/se;
  #pragma unroll
  for (int c = 0; c < 6; ++c){
    ctx[c*2048 + tid]        = enc[(size_t)tid*6 + c] * w0;
    ctx[c*2048 + tid + 1024] = enc[(size_t)(tid+1024)*6 + c] * w1;
  }
}

// ---- CNN ----
__global__ void k_conv(const float* __restrict__ in, int Lin,
                       float* __restrict__ out, int Lout,
                       const float* __restrict__ w, const float* __restrict__ b, int K){
  int idx = blockIdx.x*256 + threadIdx.x;
  if (idx >= 6*Lout) return;
  int o = idx / Lout, x = idx - o*Lout;
  float acc = b[o];
  for (int i = 0; i < 6; ++i){
    const float* ir = in + i*Lin + x;
    const float* wr = w + (o*6 + i)*K;
    for (int k = 0; k < K; ++k) acc = fmaf(ir[k], wr[k], acc);
  }
  out[o*Lout + x] = lrelu(acc);
}

__global__ void k_pool(const float* __restrict__ in, int Lin, float* __restrict__ out, int Lout){
  int idx = blockIdx.x*256 + threadIdx.x;
  if (idx >= 6*Lout) return;
  int o = idx / Lout, x = idx - o*Lout;
  out[idx] = fmaxf(in[o*Lin + 2*x], in[o*Lin + 2*x + 1]);
}

__global__ void k_bn2stats(const float* __restrict__ in, float* m6, float* i6){
  __shared__ float red[16];
  for (int c = 0; c < 6; ++c){
    float s = 0.f, s2 = 0.f;
    for (int i = threadIdx.x; i < 1006; i += 256){
      float v = in[c*1006 + i]; s += v; s2 += v*v;
    }
    s  = bred<false>(s, red);
    s2 = bred<false>(s2, red);
    if (threadIdx.x == 0){
      float m = s / 1006.f;
      float var = s2 / 1006.f - m*m;
      m6[c] = m; i6[c] = rsqrtf(var + EPS);
    }
  }
}

__global__ void k_seq(const float* __restrict__ cb4, const float* m6, const float* i6,
                      const float* g2, const float* b2, float* __restrict__ seq){
  int idx = blockIdx.x*256 + threadIdx.x;
  if (idx >= TS*6) return;
  int c = idx % 6, t = idx / 6;
  float m = m6[c], iv = i6[c], g = g2[c], b = b2[c];
  float v0 = (cb4[c*1006 + 2*t]     - m)*iv*g + b;
  float v1 = (cb4[c*1006 + 2*t + 1] - m)*iv*g + b;
  seq[idx] = fmaxf(v0, v1);
}

__global__ void k_gihat(const float* __restrict__ seq, const float* __restrict__ Wi,
                        const float* __restrict__ bi, float* __restrict__ gihat){
  int row = blockIdx.x*256 + threadIdx.x;   // < 6144
  int t = blockIdx.y;
  const float* s = seq + t*6;
  const float* w = Wi + (size_t)row*6;
  float v = fmaf(s[0],w[0], fmaf(s[1],w[1], fmaf(s[2],w[2],
            fmaf(s[3],w[3], fmaf(s[4],w[4], fmaf(s[5],w[5], bi[row]))))));
  gihat[(size_t)t*6144 + row] = v;
}

// ---- GRU: 256 co-resident WGs, LDS-resident bf16 Wh ----
// Sync protocol: relaxed agent-scope atomics ONLY (each = write-through/read-at-L3,
// no buffer_inv / buffer_wbl2 cache maintenance). Ordering h-stores -> flag-store is
// enforced manually with s_waitcnt vmcnt(0) (store vmcnt retires at coherence point).
#define GRU_SMEM (24*2048*2 + 2048*4 + 24*4 + 8*4)

__global__ void __launch_bounds__(256, 1)
k_gru(const float* __restrict__ Wh, const float* __restrict__ bh,
      const float* __restrict__ hidden, const float* __restrict__ gihat,
      float* hbuf, int* flags, float* __restrict__ xs, float* __restrict__ dout){
  extern __shared__ char smem[];
  ushort* Wl       = (ushort*)smem;                        // [24][2048] bf16
  float*  h_lds    = (float*)(smem + 24*2048*2);           // [2048]
  float*  gh_lds   = (float*)(smem + 24*2048*2 + 2048*4);  // [24]
  float*  hnew_lds = gh_lds + 24;                          // [8]
  const int tid = threadIdx.x, wg = blockIdx.x;
  const int lane = tid & 63, wave = tid >> 6;
  const int hbase = wg << 3;   // 8 h-indices per WG

  // stage & convert weights: local rows 0..7 = r, 8..15 = z, 16..23 = n
  for (int idx = tid; idx < 24*2048; idx += 256){
    int lr = idx >> 11, col = idx & 2047;
    int grow = (lr < 8) ? (hbase + lr)
             : (lr < 16) ? (2048 + hbase + lr - 8)
                         : (4096 + hbase + lr - 16);
    unsigned u = __float_as_uint(Wh[(size_t)grow*2048 + col]);
    Wl[idx] = (ushort)((u + 0x7fffu + ((u >> 16) & 1u)) >> 16);   // RNE to bf16
  }
  float bhr = 0.f, bhz = 0.f, bhn = 0.f;
  if (tid < 8){
    bhr = bh[hbase + tid];
    bhz = bh[2048 + hbase + tid];
    bhn = bh[4096 + hbase + tid];
  }
  __syncthreads();

  for (int t = 0; t < TS; ++t){
    // prefetch per-step gate biases (independent of h -> overlaps with wait)
    float gr = 0.f, gz = 0.f, gn = 0.f;
    if (tid < 8){
      const float* gp = gihat + (size_t)t*6144 + hbase + tid;
      gr = gp[0]; gz = gp[2048]; gn = gp[4096];
    }
    if (t == 0){
      for (int i = tid; i < 2048; i += 256) h_lds[i] = hidden[i];
    } else {
      // wave 0 polls all 256 flags with RELAXED loads (no cache maintenance)
      if (wave == 0){
        const int* fp = flags + lane;
        for (;;){
          int a = __hip_atomic_load(fp,       __ATOMIC_RELAXED, SCOPE_AGENT);
          int b = __hip_atomic_load(fp + 64,  __ATOMIC_RELAXED, SCOPE_AGENT);
          int c = __hip_atomic_load(fp + 128, __ATOMIC_RELAXED, SCOPE_AGENT);
          int d = __hip_atomic_load(fp + 192, __ATOMIC_RELAXED, SCOPE_AGENT);
          int m = min(min(a, b), min(c, d));
          if (__all(m >= t)) break;
          __builtin_amdgcn_s_sleep(1);
        }
      }
      __syncthreads();
      asm volatile("" ::: "memory");
      const ull* hb = (const ull*)hbuf + ((t - 1) & 1)*1024;
      for (int i = tid; i < 1024; i += 256){
        ull v = __hip_atomic_load(hb + i, __ATOMIC_RELAXED, SCOPE_AGENT);
        ((ull*)h_lds)[i] = v;
      }
    }
    __syncthreads();

    // per-lane h fragment (same layout for every row)
    float hreg[32];
    #pragma unroll
    for (int k = 0; k < 4; ++k){
      const float* hp = h_lds + 8*lane + 512*k;
      float4 a = *(const float4*)hp;
      float4 b = *(const float4*)(hp + 4);
      hreg[8*k+0]=a.x; hreg[8*k+1]=a.y; hreg[8*k+2]=a.z; hreg[8*k+3]=a.w;
      hreg[8*k+4]=b.x; hreg[8*k+5]=b.y; hreg[8*k+6]=b.z; hreg[8*k+7]=b.w;
    }
    // 24 dot products: wave w owns rows 6w..6w+5
    #pragma unroll
    for (int rr = 0; rr < 6; ++rr){
      int lr = wave*6 + rr;
      const ushort* wrow = Wl + lr*2048 + 8*lane;
      float acc = 0.f;
      #pragma unroll
      for (int k = 0; k < 4; ++k){
        uint4 wv = *(const uint4*)(wrow + (k << 9));
        acc = fmaf(bflo(wv.x), hreg[8*k+0], acc);
        acc = fmaf(bfhi(wv.x), hreg[8*k+1], acc);
        acc = fmaf(bflo(wv.y), hreg[8*k+2], acc);
        acc = fmaf(bfhi(wv.y), hreg[8*k+3], acc);
        acc = fmaf(bflo(wv.z), hreg[8*k+4], acc);
        acc = fmaf(bfhi(wv.z), hreg[8*k+5], acc);
        acc = fmaf(bflo(wv.w), hreg[8*k+6], acc);
        acc = fmaf(bfhi(wv.w), hreg[8*k+7], acc);
      }
      #pragma unroll
      for (int off = 32; off; off >>= 1) acc += __shfl_xor(acc, off);
      if (lane == 0) gh_lds[lr] = acc;
    }
    __syncthreads();
    // gate combine on 8 threads
    if (tid < 8){
      float r  = 1.f/(1.f + expf(-(gr + bhr + gh_lds[tid])));
      float z  = 1.f/(1.f + expf(-(gz + bhz + gh_lds[8 + tid])));
      float ng = tanhf(gn + r*(gh_lds[16 + tid] + bhn));
      float hold = h_lds[hbase + tid];
      float hnew = (1.f - z)*ng + z*hold;
      xs[(size_t)t*2048 + hbase + tid] = hnew;
      if (t == TS - 1) dout[4 + hbase + tid] = hnew;
      hnew_lds[tid] = hnew;
    }
    __syncthreads();
    // publish slice (write-through, packed 64-bit) then flag; vmcnt(0) orders them
    if (tid == 0){
      ull* hb = (ull*)hbuf + (t & 1)*1024 + (hbase >> 1);
      const ull* src = (const ull*)hnew_lds;
      #pragma unroll
      for (int j = 0; j < 4; ++j)
        __hip_atomic_store(hb + j, src[j], __ATOMIC_RELAXED, SCOPE_AGENT);
      asm volatile("s_waitcnt vmcnt(0)" ::: "memory");
      __hip_atomic_store(flags + wg, t + 1, __ATOMIC_RELAXED, SCOPE_AGENT);
    }
  }
}

// ---- head ----
__global__ void k_lin1(const float* __restrict__ xs, const float* __restrict__ W,
                       const float* __restrict__ B, float* __restrict__ y1){
  __shared__ float xT[32][36];
  __shared__ float wT[32][36];
  int tid = threadIdx.x;
  int m0 = blockIdx.y*32, n0 = blockIdx.x*32;
  int lm = tid >> 3, lk = (tid & 7)*4;
  int tx = tid & 15, ty = tid >> 4;
  float acc00=0.f, acc01=0.f, acc10=0.f, acc11=0.f;
  for (int k0 = 0; k0 < 2048; k0 += 32){
    float4 xv = make_float4(0.f,0.f,0.f,0.f);
    int tt = m0 + lm;
    if (tt < TS) xv = *(const float4*)(xs + (size_t)tt*2048 + k0 + lk);
    xT[lk+0][lm] = lrelu(xv.x); xT[lk+1][lm] = lrelu(xv.y);
    xT[lk+2][lm] = lrelu(xv.z); xT[lk+3][lm] = lrelu(xv.w);
    float4 wv = make_float4(0.f,0.f,0.f,0.f);
    int jj = n0 + lm;
    if (jj < 400) wv = *(const float4*)(W + (size_t)jj*2048 + k0 + lk);
    wT[lk+0][lm] = wv.x; wT[lk+1][lm] = wv.y; wT[lk+2][lm] = wv.z; wT[lk+3][lm] = wv.w;
    __syncthreads();
    #pragma unroll
    for (int k = 0; k < 32; ++k){
      float2 a = *(const float2*)&xT[k][2*ty];
      float2 b = *(const float2*)&wT[k][2*tx];
      acc00 = fmaf(a.x, b.x, acc00); acc01 = fmaf(a.x, b.y, acc01);
      acc10 = fmaf(a.y, b.x, acc10); acc11 = fmaf(a.y, b.y, acc11);
    }
    __syncthreads();
  }
  int t0 = m0 + 2*ty, j0 = n0 + 2*tx;
  if (t0 < TS){
    if (j0 < 400)   y1[t0*400 + j0]   = acc00 + B[j0];
    if (j0+1 < 400) y1[t0*400 + j0+1] = acc01 + B[j0+1];
  }
  if (t0+1 < TS){
    if (j0 < 400)   y1[(t0+1)*400 + j0]   = acc10 + B[j0];
    if (j0+1 < 400) y1[(t0+1)*400 + j0+1] = acc11 + B[j0+1];
  }
}

__global__ void k_bn3p(const float* __restrict__ y1, float* __restrict__ part){
  __shared__ float red[16];
  float s = 0.f, s2 = 0.f;
  for (int idx = blockIdx.x*256 + threadIdx.x; idx < TS*400; idx += 64*256){
    float v = y1[idx]; s += v; s2 += v*v;
  }
  s  = bred<false>(s, red);
  s2 = bred<false>(s2, red);
  if (threadIdx.x == 0){ part[blockIdx.x] = s; part[64 + blockIdx.x] = s2; }
}

__global__ void k_bn3f(const float* __restrict__ part, float* __restrict__ stats){
  int ln = threadIdx.x;
  float s = part[ln], s2 = part[64 + ln];
  #pragma unroll
  for (int off = 32; off; off >>= 1){ s += __shfl_xor(s, off); s2 += __shfl_xor(s2, off); }
  if (ln == 0){
    float m = s / (float)(TS*400);
    float var = s2 / (float)(TS*400) - m*m;
    stats[0] = m; stats[1] = rsqrtf(var + EPS);
  }
}

__global__ void k_x2(const float* __restrict__ y1, const float* __restrict__ stats,
                     const float* g3, const float* b3, const float* __restrict__ l2w,
                     const float* l2b, float* __restrict__ x2){
  int t = blockIdx.x, ln = threadIdx.x;
  float m = stats[0], iv = stats[1], g = g3[0], b = b3[0];
  float acc = 0.f;
  for (int j = ln; j < 400; j += 64)
    acc = fmaf(lrelu((y1[t*400 + j] - m)*iv*g + b), l2w[j], acc);
  #pragma unroll
  for (int off = 32; off; off >>= 1) acc += __shfl_xor(acc, off);
  if (ln == 0) x2[t] = lrelu(acc + l2b[0]);
}

__global__ void k_head(const float* __restrict__ x2, const float* __restrict__ last,
                       const float* __restrict__ l3w, const float* __restrict__ l3b,
                       const float* __restrict__ l4w, const float* __restrict__ l4b,
                       float* __restrict__ out){
  __shared__ float o1[50];
  int tid = threadIdx.x;
  if (tid < 50){
    float acc = l3b[tid];
    const float* wr = l3w + tid*507;
    for (int i = 0; i < TS; ++i) acc = fmaf(x2[i], wr[i], acc);
    for (int i = 0; i < 4; ++i)  acc = fmaf(last[i], wr[TS + i], acc);
    o1[tid] = lrelu(acc);
  }
  __syncthreads();
  if (tid < 4){
    float acc = l4b[tid];
    const float* wr = l4w + tid*50;
    for (int k = 0; k < 50; ++k) acc = fmaf(o1[k], wr[k], acc);
    out[tid] = acc;
  }
}

// ---- workspace layout (bytes) ----
#define OFF_FLAGS   0u
#define OFF_BN2M    1024u
#define OFF_BN2I    1056u
#define OFF_BN3P    2048u
#define OFF_BN3S    2560u
#define OFF_W2      4096u
#define OFF_SCORE   12288u
#define OFF_X2      20480u
#define OFF_CTX     24576u
#define OFF_CB1     73728u
#define OFF_CB2     122880u
#define OFF_CP1     172032u
#define OFF_CB3     196608u
#define OFF_CB4     221184u
#define OFF_SEQ     245760u
#define OFF_HBUF    258048u
#define OFF_GIHAT   274432u
#define OFF_XS      12636160u
#define OFF_Y1      16756736u

extern "C" void kernel_launch(void* const* d_in, const int* in_sizes, int n_in,
                              void* d_out, int out_size, void* d_ws, size_t ws_size,
                              hipStream_t stream){
  const float* last   = (const float*)d_in[0];
  const float* hidden = (const float*)d_in[1];
  const float* enc    = (const float*)d_in[2];
  const float* W1w = (const float*)d_in[3];
  const float* W1b = (const float*)d_in[4];
  const float* W2w = (const float*)d_in[5];
  const float* W2b = (const float*)d_in[6];
  const float* Vw  = (const float*)d_in[7];
  const float* Vb  = (const float*)d_in[8];
  const float* g1  = (const float*)d_in[9];
  const float* b1  = (const float*)d_in[10];
  const float* c1w = (const float*)d_in[11]; const float* c1b = (const float*)d_in[12];
  const float* c2w = (const float*)d_in[13]; const float* c2b = (const float*)d_in[14];
  const float* c3w = (const float*)d_in[15]; const float* c3b = (const float*)d_in[16];
  const float* c4w = (const float*)d_in[17]; const float* c4b = (const float*)d_in[18];
  const float* g2  = (const float*)d_in[19]; const float* b2  = (const float*)d_in[20];
  const float* Wi  = (const float*)d_in[21]; const float* Wh  = (const float*)d_in[22];
  const float* bi  = (const float*)d_in[23]; const float* bhp = (const float*)d_in[24];
  const float* l1w = (const float*)d_in[25]; const float* l1b = (const float*)d_in[26];
  const float* g3  = (const float*)d_in[27]; const float* b3  = (const float*)d_in[28];
  const float* l2w = (const float*)d_in[29]; const float* l2b = (const float*)d_in[30];
  const float* l3w = (const float*)d_in[31]; const float* l3b = (const float*)d_in[32];
  const float* l4w = (const float*)d_in[33]; const float* l4b = (const float*)d_in[34];
  float* out = (float*)d_out;
  char* ws = (char*)d_ws;

  int*   flags = (int*)(ws + OFF_FLAGS);
  float* bn2m  = (float*)(ws + OFF_BN2M);
  float* bn2i  = (float*)(ws + OFF_BN2I);
  float* bn3p  = (float*)(ws + OFF_BN3P);
  float* bn3s  = (float*)(ws + OFF_BN3S);
  float* w2v   = (float*)(ws + OFF_W2);
  float* score = (float*)(ws + OFF_SCORE);
  float* x2    = (float*)(ws + OFF_X2);
  float* ctx   = (float*)(ws + OFF_CTX);
  float* cb1   = (float*)(ws + OFF_CB1);
  float* cb2   = (float*)(ws + OFF_CB2);
  float* cp1   = (float*)(ws + OFF_CP1);
  float* cb3   = (float*)(ws + OFF_CB3);
  float* cb4   = (float*)(ws + OFF_CB4);
  float* seq   = (float*)(ws + OFF_SEQ);
  float* hbuf  = (float*)(ws + OFF_HBUF);
  float* gihat = (float*)(ws + OFF_GIHAT);
  float* xs    = (float*)(ws + OFF_XS);
  float* y1    = (float*)(ws + OFF_Y1);

  hipMemsetAsync(flags, 0, 1024, stream);

  k_w2<<<512, 256, 0, stream>>>(W2w, W2b, hidden, w2v);
  k_score<<<512, 256, 0, stream>>>(enc, W1w, W1b, Vw, Vb, w2v, score);
  k_softctx<<<1, 1024, 0, stream>>>(enc, score, g1, b1, ctx);

  k_conv<<<(6*2038 + 255)/256, 256, 0, stream>>>(ctx, 2048, cb1, 2038, c1w, c1b, 11);
  k_conv<<<(6*2028 + 255)/256, 256, 0, stream>>>(cb1, 2038, cb2, 2028, c2w, c2b, 11);
  k_pool<<<(6*1014 + 255)/256, 256, 0, stream>>>(cb2, 2028, cp1, 1014);
  k_conv<<<(6*1010 + 255)/256, 256, 0, stream>>>(cp1, 1014, cb3, 1010, c3w, c3b, 5);
  k_conv<<<(6*1006 + 255)/256, 256, 0, stream>>>(cb3, 1010, cb4, 1006, c4w, c4b, 5);
  k_bn2stats<<<1, 256, 0, stream>>>(cb4, bn2m, bn2i);
  k_seq<<<12, 256, 0, stream>>>(cb4, bn2m, bn2i, g2, b2, seq);
  k_gihat<<<dim3(24, TS), 256, 0, stream>>>(seq, Wi, bi, gihat);

  hipFuncSetAttribute((const void*)k_gru, hipFuncAttributeMaxDynamicSharedMemorySize,
                      (int)GRU_SMEM);
  void* kargs[8] = {(void*)&Wh, (void*)&bhp, (void*)&hidden, (void*)&gihat,
                    (void*)&hbuf, (void*)&flags, (void*)&xs, (void*)&out};
  hipLaunchCooperativeKernel((const void*)k_gru, dim3(256), dim3(256), kargs,
                             (unsigned)GRU_SMEM, stream);

  k_lin1<<<dim3(13, 16), 256, 0, stream>>>(xs, l1w, l1b, y1);
  k_bn3p<<<64, 256, 0, stream>>>(y1, bn3p);
  k_bn3f<<<1, 64, 0, stream>>>(bn3p, bn3s);
  k_x2<<<TS, 64, 0, stream>>>(y1, bn3s, g3, b3, l2w, l2b, x2);
  k_head<<<1, 64, 0, stream>>>(x2, last, l3w, l3b, l4w, l4b, out);
}